// Round 7
// baseline (304.838 us; speedup 1.0000x reference)
//
#include <hip/hip_runtime.h>

#define DIM 1024
#define BATCH 4
#define SEQ 4096
#define NH 16
#define HD 64
#define KP 256

typedef float f32x4 __attribute__((ext_vector_type(4)));
typedef _Float16 half8 __attribute__((ext_vector_type(8)));

// DPP row_ror:n within 16-lane rows. ctrl = 0x120|n.
#define DPPF(v, ctrl)                                                        \
  __builtin_bit_cast(float, __builtin_amdgcn_mov_dpp(                        \
                                __builtin_bit_cast(int, v), ctrl, 0xF, 0xF, true))

// Wq and Wo converts merged: grid 1024 blocks
__global__ void k_cvtw(const float* __restrict__ Wq, const float* __restrict__ Wo,
                       _Float16* __restrict__ Wq_h, _Float16* __restrict__ Wo_h) {
  int bb = blockIdx.x;
  const float* s = (bb < 512) ? Wq : Wo;
  _Float16* d = (bb < 512) ? Wq_h : Wo_h;
  int i = ((bb & 511) * 256 + threadIdx.x) * 8;
  f32x4 a = *(const f32x4*)(s + i);
  f32x4 b = *(const f32x4*)(s + i + 4);
  half8 h;
  h[0] = a[0]; h[1] = a[1]; h[2] = a[2]; h[3] = a[3];
  h[4] = b[0]; h[5] = b[1]; h[6] = b[2]; h[7] = b[3];
  *(half8*)(d + i) = h;
}

// misc small work merged: grid 88 blocks
__global__ void k_misc(const float* __restrict__ E, const float* __restrict__ F,
                       _Float16* __restrict__ E_h, _Float16* __restrict__ Ft,
                       float* __restrict__ xsum) {
  int bb = blockIdx.x;
  if (bb < 16) {
    xsum[bb * 256 + threadIdx.x] = 0.f;
  } else if (bb < 24) {
    int i = ((bb - 16) * 256 + threadIdx.x) * 8;
    f32x4 a = *(const f32x4*)(E + i);
    f32x4 b = *(const f32x4*)(E + i + 4);
    half8 h;
    h[0] = a[0]; h[1] = a[1]; h[2] = a[2]; h[3] = a[3];
    h[4] = b[0]; h[5] = b[1]; h[6] = b[2]; h[7] = b[3];
    *(half8*)(E_h + i) = h;
  } else {
    int i = (bb - 24) * 256 + threadIdx.x;  // 16384
    int k = i >> 6, d = i & 63;
    Ft[d * KP + (k & 15) * 16 + (k >> 4)] = (_Float16)F[i];
  }
}

// xsum[b,c] = sum_n x[b,n,c]; reads fp32 x directly; grid (4,B,32)
__global__ void k_xsum(const float* __restrict__ xf, float* __restrict__ xs) {
  int c = blockIdx.x * 256 + threadIdx.x;
  int b = blockIdx.y;
  int n0 = blockIdx.z * 128;
  const float* p = xf + (size_t)(b * SEQ + n0) * DIM + c;
  float s = 0.f;
  #pragma unroll 8
  for (int i = 0; i < 128; i++) s += p[i * DIM];
  atomicAdd(&xs[b * DIM + c], s);
}

// Sk[b,c] = xsum[b,:]@Wk[c,:], Sv likewise. One wave per output dot.
__global__ void k_sksv(const float* __restrict__ xs, const float* __restrict__ Wk,
                       const float* __restrict__ Wv, float* __restrict__ Sk,
                       float* __restrict__ Sv) {
  int idx = blockIdx.x * 4 + (threadIdx.x >> 6);
  int lane = threadIdx.x & 63;
  int kv = idx >> 12;
  int rem = idx & 4095;
  int b = rem >> 10, c = rem & 1023;
  const float* W = (kv ? Wv : Wk) + c * DIM;
  const float* xp = xs + b * DIM;
  float a = 0.f;
  #pragma unroll
  for (int i = 0; i < 16; i++) a += xp[lane + i * 64] * W[lane + i * 64];
  for (int off = 32; off; off >>= 1) a += __shfl_down(a, off);
  if (lane == 0) (kv ? Sv : Sk)[rem] = a;
}

// ---- fp16 MFMA GEMM, round 9: 128x128 tile @ 3 blocks/CU ----
// Rounds 0-6 postmortem: six schedule variants (2-phase, ring-4 counted
// vmcnt, 1-barrier free-run, asm ds_read, 8-phase, reg-staged) ALL plateau
// at 57-70us, MfmaUtil ~19-23% — the schedule is not the limit. The shared
// invariant: grid=256 = 1 block/CU (8 waves in barrier lockstep); every
// ds-read/wait/barrier window idles the matrix pipe with nothing to fill
// it (Occupancy ~18.6% all session). m97 evidence: a simple 2-barrier 128²
// kernel at ~3 blocks/CU reaches 912 TF — cross-BLOCK overlap (m114) fills
// the stall windows. This round: 128² tile, 4 waves/block, 32KB LDS,
// launch_bounds(256,3) -> 3 blocks/CU. Reg-staged dbuf (no gll16 alias
// hazard), single barrier per K-tile, proven conflict-free chunk swizzle.
// MODE 0 additionally fuses the fp32->fp16 x convert into A-staging
// (reads fp32 x; converts post-MFMA before ds_write) - k_cvt eliminated.
// MODE 0: out fp16 = acc * sb[b*DIM+col] * 0.125 * log2e  (Q proj, A=f32)
// MODE 1: out fp32 = acc + sb[col]                        (out proj, A=f16)
template <int MODE>
__global__ __launch_bounds__(256, 3) void k_gemm(const void* __restrict__ Ain,
                                                 const _Float16* __restrict__ Bw,
                                                 void* __restrict__ Cout,
                                                 const float* __restrict__ sb) {
  __shared__ _Float16 sh[2][2][4096];  // [dbuf][A=0/B=1][128 rows x 32 k]
  const int tid = threadIdx.x;
  const int w = tid >> 6, l = tid & 63;
  const int q4 = l >> 4, mm = l & 15;
  const int wm = w & 1, wn = w >> 1;
  const int m0 = blockIdx.x * 128, n0 = blockIdx.y * 128;
  f32x4 acc[4][4] = {};

  // staging: thread covers rows rowl, rowl+16 (4 waves x 32 = 128 rows),
  // natural global chunk (l&3); LDS write chunk = (l&3) ^ ((l>>3)&3)
  // (row-key XOR: LDS[row][c] = global[row][c ^ ((row>>1)&3)]).
  const int rowl = w * 32 + (l >> 2);
  const float* Agf = (const float*)Ain + (size_t)(m0 + rowl) * DIM + (l & 3) * 8;
  const _Float16* Agh = (const _Float16*)Ain + (size_t)(m0 + rowl) * DIM + (l & 3) * 8;
  const _Float16* Bg = Bw + (size_t)(n0 + rowl) * DIM + (l & 3) * 8;
  const int wofs = rowl * 32 + ((l & 3) ^ ((l >> 3) & 3)) * 8;
  // reader: global chunk q4 of row r stored at chunk q4 ^ ((r>>1)&3);
  // (r>>1)&3 == (mm>>1)&3 for all frag rows (bases are multiples of 16).
  const int csw = (q4 ^ ((mm >> 1) & 3)) * 8;
  const int rdo_a = (wm * 64 + mm) * 32 + csw;
  const int rdo_b = (wn * 64 + mm) * 32 + csw;

  // staging registers: MODE0 keeps raw f32 (convert AFTER the MFMA region so
  // the vmcnt wait + cvt VALU sit post-MFMA); MODE1 holds fp16 directly.
  f32x4 sa0, sa1, sa2, sa3;
  half8 ra0, ra1, rb0, rb1;

  // prologue: tile 0 -> regs -> buf0
  if constexpr (MODE == 0) {
    sa0 = *(const f32x4*)(Agf);
    sa1 = *(const f32x4*)(Agf + 4);
    sa2 = *(const f32x4*)(Agf + 16 * DIM);
    sa3 = *(const f32x4*)(Agf + 16 * DIM + 4);
    #pragma unroll
    for (int i = 0; i < 4; i++) {
      ra0[i] = (_Float16)sa0[i]; ra0[i + 4] = (_Float16)sa1[i];
      ra1[i] = (_Float16)sa2[i]; ra1[i + 4] = (_Float16)sa3[i];
    }
  } else {
    ra0 = *(const half8*)(Agh);
    ra1 = *(const half8*)(Agh + 16 * DIM);
  }
  rb0 = *(const half8*)(Bg);
  rb1 = *(const half8*)(Bg + 16 * DIM);
  *(half8*)&sh[0][0][wofs] = ra0;
  *(half8*)&sh[0][0][wofs + 512] = ra1;
  *(half8*)&sh[0][1][wofs] = rb0;
  *(half8*)&sh[0][1][wofs + 512] = rb1;
  __syncthreads();

  #pragma unroll 2
  for (int t = 0; t < 32; t++) {
    const int cur = t & 1;
    if (t < 31) {  // issue next-tile loads first: latency hides under MFMA
      const int kn = (t + 1) * 32;
      if constexpr (MODE == 0) {
        sa0 = *(const f32x4*)(Agf + kn);
        sa1 = *(const f32x4*)(Agf + kn + 4);
        sa2 = *(const f32x4*)(Agf + kn + 16 * DIM);
        sa3 = *(const f32x4*)(Agf + kn + 16 * DIM + 4);
      } else {
        ra0 = *(const half8*)(Agh + kn);
        ra1 = *(const half8*)(Agh + kn + 16 * DIM);
      }
      rb0 = *(const half8*)(Bg + kn);
      rb1 = *(const half8*)(Bg + kn + 16 * DIM);
    }
    half8 av[4], bv[4];
    const _Float16* Ap = &sh[cur][0][rdo_a];
    const _Float16* Bp = &sh[cur][1][rdo_b];
    #pragma unroll
    for (int i = 0; i < 4; i++) bv[i] = *(const half8*)(Bp + i * 512);
    #pragma unroll
    for (int i = 0; i < 4; i++) av[i] = *(const half8*)(Ap + i * 512);
    __builtin_amdgcn_s_setprio(1);
    #pragma unroll
    for (int mt = 0; mt < 4; mt++)
      #pragma unroll
      for (int nt = 0; nt < 4; nt++)
        acc[mt][nt] = __builtin_amdgcn_mfma_f32_16x16x32_f16(av[mt], bv[nt], acc[mt][nt], 0, 0, 0);
    __builtin_amdgcn_s_setprio(0);
    __builtin_amdgcn_sched_barrier(0);  // keep vmcnt-wait + cvt + ds_write below MFMA
    if (t < 31) {
      if constexpr (MODE == 0) {
        #pragma unroll
        for (int i = 0; i < 4; i++) {
          ra0[i] = (_Float16)sa0[i]; ra0[i + 4] = (_Float16)sa1[i];
          ra1[i] = (_Float16)sa2[i]; ra1[i + 4] = (_Float16)sa3[i];
        }
      }
      _Float16* dA = &sh[cur ^ 1][0][wofs];
      _Float16* dB = &sh[cur ^ 1][1][wofs];
      *(half8*)dA = ra0;
      *(half8*)(dA + 512) = ra1;
      *(half8*)dB = rb0;
      *(half8*)(dB + 512) = rb1;
    }
    __syncthreads();
  }

  if (MODE == 0) {
    _Float16* Lh = (_Float16*)sh;  // [64][136] fp16 per phase (padded)
    const float lsc = 0.125f * 1.44269504088896f;
    #pragma unroll
    for (int p = 0; p < 2; p++) {
      if (wm == p) {
        #pragma unroll
        for (int nt = 0; nt < 4; nt++) {
          const int cl = wn * 64 + nt * 16 + mm;
          const float s = sb[(m0 >> 12) * DIM + n0 + cl] * lsc;
          #pragma unroll
          for (int mt = 0; mt < 4; mt++) {
            const int rl = mt * 16 + q4 * 4;
            #pragma unroll
            for (int r = 0; r < 4; r++)
              Lh[(rl + r) * 136 + cl] = (_Float16)(acc[mt][nt][r] * s);
          }
        }
      }
      __syncthreads();
      const int row_l = tid >> 2, c0 = (tid & 3) * 32;
      _Float16* dst = (_Float16*)Cout + (size_t)(m0 + p * 64 + row_l) * DIM + n0 + c0;
      #pragma unroll
      for (int i = 0; i < 4; i++)
        *(half8*)(dst + i * 8) = *(half8*)(Lh + row_l * 136 + c0 + i * 8);
      __syncthreads();
    }
  } else {
    float* Lf = (float*)sh;  // [32][132] f32 per phase (padded)
    #pragma unroll
    for (int p = 0; p < 4; p++) {
      if (wm == (p >> 1)) {
        #pragma unroll
        for (int nt = 0; nt < 4; nt++) {
          const int cl = wn * 64 + nt * 16 + mm;
          const float s = sb[n0 + cl];
          #pragma unroll
          for (int mti = 0; mti < 2; mti++) {
            const int mt = (p & 1) * 2 + mti;
            const int rl = mt * 16 + q4 * 4 - (p & 1) * 32;
            #pragma unroll
            for (int r = 0; r < 4; r++)
              Lf[(rl + r) * 132 + cl] = acc[mt][nt][r] + s;
          }
        }
      }
      __syncthreads();
      const int row_l = tid >> 3, c0 = (tid & 7) * 16;
      float* dst = (float*)Cout + (size_t)(m0 + p * 32 + row_l) * DIM + n0 + c0;
      #pragma unroll
      for (int i = 0; i < 4; i++)
        *(f32x4*)(dst + i * 4) = *(f32x4*)(Lf + row_l * 132 + c0 + i * 4);
      __syncthreads();
    }
  }
}

// ---- fused attention v4: grid (8,64)=512 blocks, 8 tiles/wave ----
__global__ __launch_bounds__(256) void k_attn(const _Float16* __restrict__ Q,
                                              const _Float16* __restrict__ E,
                                              const _Float16* __restrict__ Ftp,
                                              const float* __restrict__ Sv,
                                              _Float16* __restrict__ O) {
  __shared__ _Float16 Ps[4][16][264];
  const int tid = threadIdx.x;
  const int w = tid >> 6, lane = tid & 63;
  const int q4 = lane >> 4, mm = lane & 15;
  const int bh = blockIdx.y;
  const int b = bh >> 4, h = bh & 15;
  const int row_base = blockIdx.x * 512 + w * 128;  // 8 tiles of 16 rows

  half8 ef[16][2];
  #pragma unroll
  for (int t = 0; t < 16; t++)
    #pragma unroll
    for (int kk = 0; kk < 2; kk++)
      ef[t][kk] = *(const half8*)(E + (t * 16 + mm) * HD + kk * 32 + q4 * 8);
  half8 ff[4][8];
  #pragma unroll
  for (int nt = 0; nt < 4; nt++)
    #pragma unroll
    for (int kk = 0; kk < 8; kk++)
      ff[nt][kk] = *(const half8*)(Ftp + (nt * 16 + mm) * KP + kk * 32 + q4 * 8);
  float sv[4];
  #pragma unroll
  for (int nt = 0; nt < 4; nt++) sv[nt] = Sv[b * DIM + h * HD + nt * 16 + mm];

  const _Float16* Qbase = Q + ((size_t)(b * SEQ + row_base + mm)) * DIM + h * HD + q4 * 8;
  half8 qa0 = *(const half8*)(Qbase);
  half8 qa1 = *(const half8*)(Qbase + 32);

  for (int tile = 0; tile < 8; tile++) {
    f32x4 acc[16] = {};
    #pragma unroll
    for (int t = 0; t < 16; t++)
      acc[t] = __builtin_amdgcn_mfma_f32_16x16x32_f16(qa0, ef[t][0], acc[t], 0, 0, 0);
    #pragma unroll
    for (int t = 0; t < 16; t++)
      acc[t] = __builtin_amdgcn_mfma_f32_16x16x32_f16(qa1, ef[t][1], acc[t], 0, 0, 0);
    half8 qn0, qn1;
    if (tile < 7) {
      const _Float16* Qn = Qbase + (size_t)(tile + 1) * 16 * DIM;
      qn0 = *(const half8*)(Qn);
      qn1 = *(const half8*)(Qn + 32);
    }
    float mx[4] = {-1e30f, -1e30f, -1e30f, -1e30f};
    #pragma unroll
    for (int t = 0; t < 16; t++)
      #pragma unroll
      for (int r = 0; r < 4; r++) mx[r] = fmaxf(mx[r], acc[t][r]);
    #pragma unroll
    for (int r = 0; r < 4; r++) {
      float m = mx[r];
      m = fmaxf(m, DPPF(m, 0x121));
      m = fmaxf(m, DPPF(m, 0x122));
      m = fmaxf(m, DPPF(m, 0x124));
      m = fmaxf(m, DPPF(m, 0x128));
      mx[r] = m;
    }
    float sm[4] = {0.f, 0.f, 0.f, 0.f};
    #pragma unroll
    for (int t = 0; t < 16; t++)
      #pragma unroll
      for (int r = 0; r < 4; r++) {
        float p = __builtin_amdgcn_exp2f(acc[t][r] - mx[r]);
        acc[t][r] = p;
        sm[r] += p;
      }
    #pragma unroll
    for (int r = 0; r < 4; r++) {
      float s = sm[r];
      s += DPPF(s, 0x121);
      s += DPPF(s, 0x122);
      s += DPPF(s, 0x124);
      s += DPPF(s, 0x128);
      sm[r] = 1.f / s;
    }
    #pragma unroll
    for (int r = 0; r < 4; r++) {
      half8 h0, h1;
      #pragma unroll
      for (int t = 0; t < 8; t++) h0[t] = (_Float16)acc[t][r];
      #pragma unroll
      for (int t = 0; t < 8; t++) h1[t] = (_Float16)acc[t + 8][r];
      *(half8*)&Ps[w][q4 * 4 + r][mm * 16] = h0;
      *(half8*)&Ps[w][q4 * 4 + r][mm * 16 + 8] = h1;
    }
    f32x4 acc2[4] = {};
    #pragma unroll
    for (int kk = 0; kk < 8; kk++) {
      half8 pa = *(const half8*)&Ps[w][mm][kk * 32 + q4 * 8];
      #pragma unroll
      for (int nt = 0; nt < 4; nt++)
        acc2[nt] = __builtin_amdgcn_mfma_f32_16x16x32_f16(pa, ff[nt][kk], acc2[nt], 0, 0, 0);
    }
    const int rw0 = row_base + tile * 16;
    #pragma unroll
    for (int nt = 0; nt < 4; nt++)
      #pragma unroll
      for (int r = 0; r < 4; r++)
        O[(size_t)(b * SEQ + rw0 + q4 * 4 + r) * DIM + h * HD + nt * 16 + mm] =
            (_Float16)(acc2[nt][r] * (sm[r] * sv[nt]));
    qa0 = qn0;
    qa1 = qn1;
  }
}

extern "C" void kernel_launch(void* const* d_in, const int* in_sizes, int n_in,
                              void* d_out, int out_size, void* d_ws, size_t ws_size,
                              hipStream_t stream) {
  (void)in_sizes; (void)n_in; (void)out_size; (void)ws_size;
  const float* x  = (const float*)d_in[0];
  const float* Wq = (const float*)d_in[1];
  const float* Wk = (const float*)d_in[2];
  const float* Wv = (const float*)d_in[3];
  const float* E  = (const float*)d_in[4];
  const float* F  = (const float*)d_in[5];
  const float* Wo = (const float*)d_in[6];
  const float* bo = (const float*)d_in[7];
  char* ws = (char*)d_ws;
  _Float16* O_h  = (_Float16*)(ws);          // attn output (fp16)
  _Float16* Q_h  = (_Float16*)(ws + 33554432);
  _Float16* Wq_h = (_Float16*)(ws + 67108864);
  _Float16* Wo_h = (_Float16*)(ws + 69206016);
  _Float16* E_h  = (_Float16*)(ws + 71303168);
  _Float16* Ft_h = (_Float16*)(ws + 71335936);
  float* xsum    = (float*)(ws + 71368704);
  float* Sk      = (float*)(ws + 71385088);
  float* Sv      = (float*)(ws + 71401472);
  float* out     = (float*)d_out;

  k_misc<<<88, 256, 0, stream>>>(E, F, E_h, Ft_h, xsum);
  k_cvtw<<<1024, 256, 0, stream>>>(Wq, Wo, Wq_h, Wo_h);
  k_xsum<<<dim3(4, BATCH, 32), 256, 0, stream>>>(x, xsum);
  k_sksv<<<2048, 256, 0, stream>>>(xsum, Wk, Wv, Sk, Sv);
  k_gemm<0><<<dim3(128, 8), 256, 0, stream>>>((const void*)x, Wq_h, (void*)Q_h, Sk);
  k_attn<<<dim3(8, 64), 256, 0, stream>>>(Q_h, E_h, Ft_h, Sv, O_h);
  k_gemm<1><<<dim3(128, 8), 256, 0, stream>>>((const void*)O_h, Wo_h, (void*)out, bo);
}